// Round 2
// baseline (77.037 us; speedup 1.0000x reference)
//
#include <hip/hip_runtime.h>

// ChamferDistanceMatrixL2: B=32, G=64, N=32, C=3.
// out[b][g1][g2] = mean_n min_m d(n,m) + mean_m min_n d(n,m),
// d(n,m) = s1 + s2 - 2*dot.
//
// v3: minimum-instruction fp32 form, 5.0 VALU per distance pair:
//   t(n,m) = fma(x1,qx, fma(y1,qy, fma(z1,qz, s2[m])))  // = s2 - 2*dot, 3 FMA
//   row:  min_m d = s1 + min_m t  -> s1 hoisted out of the min chain;
//         rmin accumulated pairwise via v_min3 (0.5 op/pair)
//   col:  n processed in pairs so colmin[m] = min3(colmin, t0+s1a, t1+s1b)
//         (1 add + 0.5 min3 per pair)
// One thread per output element (lane = g2, wave = g1: p1 scalar-loaded via
// readfirstlane). No LDS, no shuffles, no barriers. ~190 VGPR, 2 waves/SIMD
// (occupancy proven irrelevant by v2's null), 2048 waves fill 1024 SIMDs x2.

__global__ __launch_bounds__(256, 2)
void chamfer_dist_kernel(const float* __restrict__ xyz1,
                         const float* __restrict__ xyz2,
                         float* __restrict__ out) {
    const int b  = blockIdx.x >> 4;                               // 0..31
    const int g1 = ((blockIdx.x & 15) << 2) | (threadIdx.x >> 6); // 0..63
    const int g2 = threadIdx.x & 63;                              // 0..63

    // ---- register-cache group g2: q = -2*p2, s2 = |p2|^2 (float4 loads) ----
    const float4* __restrict__ p2v =
        reinterpret_cast<const float4*>(xyz2 + (size_t)(b * 64 + g2) * 96);

    float qx[32], qy[32], qz[32], s2[32], colmin[32];
#pragma unroll
    for (int i = 0; i < 8; ++i) {
        const float4 va = p2v[3 * i + 0];
        const float4 vb = p2v[3 * i + 1];
        const float4 vc = p2v[3 * i + 2];
        const float f[12] = {va.x, va.y, va.z, va.w,
                             vb.x, vb.y, vb.z, vb.w,
                             vc.x, vc.y, vc.z, vc.w};
#pragma unroll
        for (int j = 0; j < 4; ++j) {
            const int m = 4 * i + j;
            const float x = f[3 * j + 0];
            const float y = f[3 * j + 1];
            const float z = f[3 * j + 2];
            s2[m] = fmaf(x, x, fmaf(y, y, z * z));
            qx[m] = -2.0f * x;
            qy[m] = -2.0f * y;
            qz[m] = -2.0f * z;
            colmin[m] = 3.0e38f;
        }
    }

    // ---- wave-uniform p1 pointer -> scalar loads from K$ ----
    const int off1 = __builtin_amdgcn_readfirstlane((b * 64 + g1) * 96);
    const float* __restrict__ p1 = xyz1 + off1;

    float sum1 = 0.0f;

#pragma unroll 2
    for (int n = 0; n < 32; n += 2) {
        const float xa = p1[3 * n + 0];   // uniform -> s_load, const offset
        const float ya = p1[3 * n + 1];
        const float za = p1[3 * n + 2];
        const float xb = p1[3 * n + 3];
        const float yb = p1[3 * n + 4];
        const float zb = p1[3 * n + 5];
        const float s1a = fmaf(xa, xa, fmaf(ya, ya, za * za));
        const float s1b = fmaf(xb, xb, fmaf(yb, yb, zb * zb));
        float ra = 3.0e38f, rb = 3.0e38f;
#pragma unroll
        for (int m = 0; m < 32; m += 2) {
            const float t00 = fmaf(xa, qx[m    ], fmaf(ya, qy[m    ], fmaf(za, qz[m    ], s2[m    ])));
            const float t01 = fmaf(xa, qx[m + 1], fmaf(ya, qy[m + 1], fmaf(za, qz[m + 1], s2[m + 1])));
            const float t10 = fmaf(xb, qx[m    ], fmaf(yb, qy[m    ], fmaf(zb, qz[m    ], s2[m    ])));
            const float t11 = fmaf(xb, qx[m + 1], fmaf(yb, qy[m + 1], fmaf(zb, qz[m + 1], s2[m + 1])));
            ra = fminf(fminf(t00, t01), ra);                         // -> v_min3
            rb = fminf(fminf(t10, t11), rb);                         // -> v_min3
            colmin[m    ] = fminf(fminf(t00 + s1a, t10 + s1b), colmin[m    ]); // -> v_min3
            colmin[m + 1] = fminf(fminf(t01 + s1a, t11 + s1b), colmin[m + 1]); // -> v_min3
        }
        sum1 += (s1a + ra) + (s1b + rb);   // s1 re-added after the hoisted min
    }

    float sum2 = 0.0f;
#pragma unroll
    for (int m = 0; m < 32; ++m) sum2 += colmin[m];

    out[(size_t)(b * 64 + g1) * 64 + g2] = (sum1 + sum2) * (1.0f / 32.0f);
}

extern "C" void kernel_launch(void* const* d_in, const int* in_sizes, int n_in,
                              void* d_out, int out_size, void* d_ws, size_t ws_size,
                              hipStream_t stream) {
    const float* xyz1 = (const float*)d_in[0];
    const float* xyz2 = (const float*)d_in[1];
    float* out = (float*)d_out;

    dim3 grid(512);   // 32 b * 16 g1-quads
    dim3 block(256);  // 4 waves (g1) * 64 lanes (g2)
    chamfer_dist_kernel<<<grid, block, 0, stream>>>(xyz1, xyz2, out);
}